// Round 6
// baseline (973.838 us; speedup 1.0000x reference)
//
#include <hip/hip_runtime.h>
#include <hip/hip_bf16.h>

// Problem constants
constexpr int BB = 32;     // batch
constexpr int NN = 4096;   // tokens
constexpr int CC = 128;    // feat channels
constexpr int DD = 64;     // slot dim
constexpr int KK = 8;      // slots (slot 0 = bg, 1..7 = fg)
constexpr int HH = 128;    // mlp hidden
constexpr float SCALE = 0.125f;   // D^-0.5
constexpr float EPS_A = 1e-8f;
constexpr float LN_EPS = 1e-5f;

typedef __bf16 bfx8 __attribute__((ext_vector_type(8)));
typedef float f32x4 __attribute__((ext_vector_type(4)));

__device__ inline float wave_sum(float x) {
#pragma unroll
    for (int off = 32; off > 0; off >>= 1) x += __shfl_xor(x, off, 64);
    return x;
}

__device__ inline float lane_bcast(float v, int src) {
    return __uint_as_float(__builtin_amdgcn_readlane(__float_as_uint(v), src));
}

__device__ inline float sigmoidf_(float x) { return 1.f / (1.f + __expf(-x)); }

__device__ inline unsigned short bf16rne(float x) {
    unsigned u = __float_as_uint(x);
    unsigned r = u + 0x7fffu + ((u >> 16) & 1u);
    return (unsigned short)(r >> 16);
}
__device__ inline float bf16tof(unsigned short h) {
    return __uint_as_float(((unsigned)h) << 16);
}

struct Args {
    const float *feat, *slot_in, *nf_g, *nf_b, *Wk, *Wv;
    const float *qln_g, *qln_b, *Wq, *qbg_g, *qbg_b, *Wqbg;
    const float *gru_bih, *gru_bhh, *gbg_bih, *gbg_bhh;
    const float *res_g, *res_b, *res_w1, *res_b1, *res_w2, *res_b2;
    const float *rbg_g, *rbg_b, *rbg_w1, *rbg_b1, *rbg_w2, *rbg_b2;
    unsigned short *fragW;           // ws
    float *wT, *kT, *v;              // ws
    float *out_slots, *out_attn;
};

// ---------------------------------------------------------------------------
// prep: blocks 0-63 build fragW ([ks][nf][lane][j] bf16 of [Wk|Wv]);
// blocks 64-255 build wT[m][64][192] transposed GRU weights
// (m: 0=fg_ih 1=fg_hh 2=bg_ih 3=bg_hh).
// ---------------------------------------------------------------------------
__global__ __launch_bounds__(256) void prep(
    const float* __restrict__ Wk, const float* __restrict__ Wv,
    const float* __restrict__ fg_ih, const float* __restrict__ fg_hh,
    const float* __restrict__ bg_ih, const float* __restrict__ bg_hh,
    unsigned short* __restrict__ fragW, float* __restrict__ wT)
{
    const int gid = blockIdx.x, tid = threadIdx.x;
    if (gid < 64) {
        const int o = gid * 256 + tid;   // < 16384
        const int j = o & 7, l = (o >> 3) & 63, nf = (o >> 9) & 7, ks = o >> 12;
        const int c = ks * 32 + ((l >> 4) << 3) + j;
        const int n = nf * 16 + (l & 15);
        const float w = (n < DD) ? Wk[c * DD + n] : Wv[c * DD + (n - DD)];
        fragW[o] = bf16rne(w);
    } else {
        const int o = (gid - 64) * 256 + tid;   // < 49152
        const int m = o / (DD * 3 * DD);
        const int rem = o % (DD * 3 * DD);
        const int d = rem / (3 * DD), j = rem % (3 * DD);
        const float* W = (m == 0) ? fg_ih : (m == 1) ? fg_hh
                       : (m == 2) ? bg_ih : bg_hh;
        wT[o] = W[j * DD + d];
    }
}

// ---------------------------------------------------------------------------
// K1 (verbatim round-3, verified): x = LN(feat); [k|v] = x @ W via bf16 MFMA
// with 2-term split.  2048 blocks x 256 thr; LDS 32 KB; 4 blocks/CU.
// Outputs kT[b][d][n] (transposed via padded LDS) and v[b][n][d].
// ---------------------------------------------------------------------------
__global__ __launch_bounds__(256, 4) void k1_mfma(
    const float* __restrict__ feat, const float* __restrict__ nf_g,
    const float* __restrict__ nf_b, const unsigned short* __restrict__ fragW,
    float* __restrict__ kT, float* __restrict__ vout)
{
    __shared__ __align__(16) char ubuf[32768];
    const int tid = threadIdx.x, w = tid >> 6, lane = tid & 63;
    const size_t row0 = (size_t)blockIdx.x * 64;
    const float2 g2 = *(const float2*)&nf_g[2 * lane];
    const float2 b2 = *(const float2*)&nf_b[2 * lane];
#pragma unroll 4
    for (int r0 = 0; r0 < 16; r0++) {
        const int r = w * 16 + r0;
        const float2 x2 = *(const float2*)&feat[(row0 + r) * CC + 2 * lane];
        const float m = wave_sum(x2.x + x2.y) * (1.f / 128.f);
        const float d0 = x2.x - m, d1 = x2.y - m;
        const float var = wave_sum(d0 * d0 + d1 * d1) * (1.f / 128.f);
        const float rs = rsqrtf(var + LN_EPS);
        const float y0 = d0 * rs * g2.x + b2.x;
        const float y1 = d1 * rs * g2.y + b2.y;
        const unsigned short h0 = bf16rne(y0), h1 = bf16rne(y1);
        const unsigned short l0 = bf16rne(y0 - bf16tof(h0));
        const unsigned short l1 = bf16rne(y1 - bf16tof(h1));
        const int off = r * 256 + ((4 * lane) ^ ((r & 7) << 4));
        *(unsigned*)(ubuf + off) = (unsigned)h0 | ((unsigned)h1 << 16);
        *(unsigned*)(ubuf + 16384 + off) = (unsigned)l0 | ((unsigned)l1 << 16);
    }
    __syncthreads();
    f32x4 acc[8];
#pragma unroll
    for (int nf = 0; nf < 8; nf++) acc[nf] = (f32x4){0.f, 0.f, 0.f, 0.f};
    const int arow = w * 16 + (lane & 15);
    const int hi16 = lane >> 4;
    const int asw = (arow & 7) << 4;
#pragma unroll
    for (int ks = 0; ks < 4; ks++) {
        const int abyte = arow * 256 + ((ks * 64 + hi16 * 16) ^ asw);
        const bfx8 ah = __builtin_bit_cast(bfx8, *(const uint4*)(ubuf + abyte));
        const bfx8 al = __builtin_bit_cast(bfx8, *(const uint4*)(ubuf + 16384 + abyte));
#pragma unroll
        for (int nf = 0; nf < 8; nf++) {
            const bfx8 bw = __builtin_bit_cast(
                bfx8, *(const uint4*)(fragW + ((ks * 8 + nf) * 64 + lane) * 8));
            acc[nf] = __builtin_amdgcn_mfma_f32_16x16x32_bf16(ah, bw, acc[nf], 0, 0, 0);
            acc[nf] = __builtin_amdgcn_mfma_f32_16x16x32_bf16(al, bw, acc[nf], 0, 0, 0);
        }
    }
    __syncthreads();
    float* kslds = (float*)ubuf;
    const int trow = w * 16 + (lane >> 4) * 4;
#pragma unroll
    for (int nf = 0; nf < 4; nf++) {
        const int d = nf * 16 + (lane & 15);
#pragma unroll
        for (int reg = 0; reg < 4; reg++)
            kslds[d * 65 + trow + reg] = acc[nf][reg];
    }
    {
        const size_t vbase = (row0 + trow) * DD + (lane & 15);
#pragma unroll
        for (int nf = 4; nf < 8; nf++) {
#pragma unroll
            for (int reg = 0; reg < 4; reg++)
                vout[vbase + (size_t)reg * DD + (nf - 4) * 16] = acc[nf][reg];
        }
    }
    __syncthreads();
    const int b = (int)(row0 >> 12);
    const int n0 = (int)(row0 & 4095);
#pragma unroll
    for (int t = 0; t < 16; t++) {
        const int idx = t * 256 + tid;
        const int d = idx >> 6, nn = idx & 63;
        kT[((size_t)b * DD + d) * NN + n0 + nn] = kslds[d * 65 + nn];
    }
}

// ---------------------------------------------------------------------------
// iter_all: ONE launch for init + all 3 iterations.  One block per batch b
// (32 blocks x 1024 thr = 16 waves).  Per iter: 16 waves x 4 tiles of 64
// tokens (dots via qT[d][i] float4 LDS broadcast; softmax lane-local over 8
// slots; U-accum via al[tt][i] float4 LDS broadcast, al overlaid on Uw[w]);
// block-reduce U/S in LDS; waves 0-7 do GRU+MLP slot update + next-q.
// All cross-phase sync is __syncthreads (block-local) — no grid sync.
// ---------------------------------------------------------------------------
__global__ __launch_bounds__(1024, 1) void iter_all(Args A)
{
    const int b = blockIdx.x;
    const int tid = threadIdx.x, w = tid >> 6, lane = tid & 63;

    __shared__ __align__(16) float Uw[16][KK * DD];     // 32 KB (al scratch overlays Uw[w])
    __shared__ __align__(16) float Sw[16][KK];          // 512 B
    __shared__ __align__(16) float qT[DD][KK];          // 2 KB, [d][i]
    __shared__ __align__(16) float slots_lds[KK][DD];   // 2 KB

    // ---------------- init: waves 0-7 -> slot i = w ----------------
    if (w < KK) {
        const int i = w, fg = (i != 0);
        const float h = A.slot_in[((size_t)b * KK + i) * DD + lane];
        slots_lds[i][lane] = h;
        const float m2 = wave_sum(h) * (1.f / DD);
        const float d2 = h - m2;
        const float v2 = wave_sum(d2 * d2) * (1.f / DD);
        const float lq = d2 * rsqrtf(v2 + LN_EPS) * (fg ? A.qln_g : A.qbg_g)[lane] +
                         (fg ? A.qln_b : A.qbg_b)[lane];
        const float* W = fg ? A.Wq : A.Wqbg;
        float qv = 0.f;
#pragma unroll 4
        for (int e = 0; e < DD; e++)
            qv += lane_bcast(lq, e) * W[e * DD + lane];
        qT[lane][i] = qv;
    }
    __syncthreads();

    for (int it = 0; it < 3; it++) {
        // ---------------- attention: all 16 waves, 4 tiles each ----------
        float Uacc[KK], Sacc[KK];
#pragma unroll
        for (int i = 0; i < KK; i++) { Uacc[i] = 0.f; Sacc[i] = 0.f; }
        float* al = &Uw[w][0];   // per-wave [64][8] scratch

        for (int t = 0; t < 4; t++) {
            const int tile = w * 4 + t;
            const int n = tile * 64 + lane;

            // phase A: lane owns token n; dots over d with qT broadcast
            float dots[KK];
#pragma unroll
            for (int i = 0; i < KK; i++) dots[i] = 0.f;
            const float* kp = A.kT + (size_t)b * DD * NN + n;
#pragma unroll
            for (int half = 0; half < 2; half++) {
                float kvv[32];
#pragma unroll
                for (int d = 0; d < 32; d++)
                    kvv[d] = kp[(size_t)(half * 32 + d) * NN];
#pragma unroll
                for (int d = 0; d < 32; d++) {
                    const float k_ = kvv[d];
                    const int dd = half * 32 + d;
                    const float4 q0 = *(const float4*)&qT[dd][0];
                    const float4 q1 = *(const float4*)&qT[dd][4];
                    dots[0] += k_ * q0.x; dots[1] += k_ * q0.y;
                    dots[2] += k_ * q0.z; dots[3] += k_ * q0.w;
                    dots[4] += k_ * q1.x; dots[5] += k_ * q1.y;
                    dots[6] += k_ * q1.z; dots[7] += k_ * q1.w;
                }
            }
            float mx = -1e30f;
#pragma unroll
            for (int i = 0; i < KK; i++) { dots[i] *= SCALE; mx = fmaxf(mx, dots[i]); }
            float s = 0.f, e[KK];
#pragma unroll
            for (int i = 0; i < KK; i++) { e[i] = __expf(dots[i] - mx); s += e[i]; }
            const float inv = 1.f / s;
            float a[KK];
#pragma unroll
            for (int i = 0; i < KK; i++) { a[i] = e[i] * inv + EPS_A; Sacc[i] += a[i]; }

            if (it == 2) {
#pragma unroll
                for (int i = 0; i < KK; i++)
                    A.out_attn[((size_t)b * KK + i) * NN + n] = a[i];
            }

            // stash attn tile in this wave's al scratch (read back broadcast)
            *(float4*)&al[lane * 8]     = make_float4(a[0], a[1], a[2], a[3]);
            *(float4*)&al[lane * 8 + 4] = make_float4(a[4], a[5], a[6], a[7]);

            // phase B: lane owns d; iterate the tile's 64 tokens
            const float* vp = A.v + ((size_t)b * NN + tile * 64) * DD + lane;
#pragma unroll
            for (int half = 0; half < 2; half++) {
                float vv[32];
#pragma unroll
                for (int tt = 0; tt < 32; tt++)
                    vv[tt] = vp[(half * 32 + tt) * DD];
#pragma unroll
                for (int tt = 0; tt < 32; tt++) {
                    const int ttt = half * 32 + tt;
                    const float4 a0 = *(const float4*)&al[ttt * 8];
                    const float4 a1 = *(const float4*)&al[ttt * 8 + 4];
                    const float vx = vv[tt];
                    Uacc[0] += a0.x * vx; Uacc[1] += a0.y * vx;
                    Uacc[2] += a0.z * vx; Uacc[3] += a0.w * vx;
                    Uacc[4] += a1.x * vx; Uacc[5] += a1.y * vx;
                    Uacc[6] += a1.z * vx; Uacc[7] += a1.w * vx;
                }
            }
        }

        // commit per-wave partials (overwrites al scratch — last use was above)
#pragma unroll
        for (int i = 0; i < KK; i++) Uw[w][i * DD + lane] = Uacc[i];
        float sv[KK];
#pragma unroll
        for (int i = 0; i < KK; i++) sv[i] = wave_sum(Sacc[i]);
        if (lane == 0) {
#pragma unroll
            for (int i = 0; i < KK; i++) Sw[w][i] = sv[i];
        }
        __syncthreads();

        // ---------------- slot update: waves 0-7, slot i = w -------------
        if (w < KK) {
            const int i = w, fg = (i != 0);
            float Us = 0.f;
#pragma unroll
            for (int ww = 0; ww < 16; ww++) Us += Uw[ww][i * DD + lane];
            float Ss = 0.f;
#pragma unroll
            for (int ww = 0; ww < 16; ww++) Ss += Sw[ww][i];
            const float upd = Us / Ss;
            const float h = slots_lds[i][lane];

            // GRU (verified round-5 code; weights from wT[m][d][192])
            const float* wih = A.wT + (size_t)(fg ? 0 : 2) * (DD * 3 * DD);
            const float* whh = wih + DD * 3 * DD;
            const float* bih = fg ? A.gru_bih : A.gbg_bih;
            const float* bhh = fg ? A.gru_bhh : A.gbg_bhh;
            float gi0 = bih[lane], gi1 = bih[DD + lane], gi2 = bih[2 * DD + lane];
            float gh0 = bhh[lane], gh1 = bhh[DD + lane], gh2 = bhh[2 * DD + lane];
#pragma unroll 4
            for (int d = 0; d < DD; d++) {
                const float ud = lane_bcast(upd, d);
                const float hd = lane_bcast(h, d);
                gi0 += ud * wih[d * 192 + lane];
                gi1 += ud * wih[d * 192 + DD + lane];
                gi2 += ud * wih[d * 192 + 2 * DD + lane];
                gh0 += hd * whh[d * 192 + lane];
                gh1 += hd * whh[d * 192 + DD + lane];
                gh2 += hd * whh[d * 192 + 2 * DD + lane];
            }
            const float r = sigmoidf_(gi0 + gh0);
            const float z = sigmoidf_(gi1 + gh1);
            const float ng = tanhf(gi2 + r * gh2);
            const float tmp = (1.f - z) * ng + z * h;

            // residual MLP
            const float m = wave_sum(tmp) * (1.f / DD);
            const float dv = tmp - m;
            const float var = wave_sum(dv * dv) * (1.f / DD);
            const float lnx = dv * rsqrtf(var + LN_EPS) *
                                  (fg ? A.res_g : A.rbg_g)[lane] +
                              (fg ? A.res_b : A.rbg_b)[lane];
            const float* w1 = fg ? A.res_w1 : A.rbg_w1;
            const float* b1 = fg ? A.res_b1 : A.rbg_b1;
            float a0 = b1[lane], a1 = b1[DD + lane];
#pragma unroll 4
            for (int d = 0; d < DD; d++) {
                const float xd = lane_bcast(lnx, d);
                a0 += xd * w1[d * HH + lane];
                a1 += xd * w1[d * HH + DD + lane];
            }
            a0 = fmaxf(a0, 0.f); a1 = fmaxf(a1, 0.f);
            const float* w2 = fg ? A.res_w2 : A.rbg_w2;
            float o = (fg ? A.res_b2 : A.rbg_b2)[lane];
#pragma unroll 4
            for (int j = 0; j < DD; j++)
                o += lane_bcast(a0, j) * w2[j * DD + lane];
#pragma unroll 4
            for (int j = 0; j < DD; j++)
                o += lane_bcast(a1, j) * w2[(DD + j) * DD + lane];
            const float newh = tmp + o;

            slots_lds[i][lane] = newh;
            if (it == 2)
                A.out_slots[((size_t)b * KK + i) * DD + lane] = newh;

            // next q = LN(newh) @ Wq
            const float m2 = wave_sum(newh) * (1.f / DD);
            const float d2 = newh - m2;
            const float v2 = wave_sum(d2 * d2) * (1.f / DD);
            const float lq = d2 * rsqrtf(v2 + LN_EPS) *
                                 (fg ? A.qln_g : A.qbg_g)[lane] +
                             (fg ? A.qln_b : A.qbg_b)[lane];
            const float* W = fg ? A.Wq : A.Wqbg;
            float qv = 0.f;
#pragma unroll 4
            for (int e = 0; e < DD; e++)
                qv += lane_bcast(lq, e) * W[e * DD + lane];
            qT[lane][i] = qv;
        }
        __syncthreads();
    }
}

// ---------------------------------------------------------------------------
extern "C" void kernel_launch(void* const* d_in, const int* in_sizes, int n_in,
                              void* d_out, int out_size, void* d_ws, size_t ws_size,
                              hipStream_t stream)
{
    Args a;
    a.feat    = (const float*)d_in[0];
    a.slot_in = (const float*)d_in[1];
    a.nf_g    = (const float*)d_in[2];
    a.nf_b    = (const float*)d_in[3];
    a.Wk      = (const float*)d_in[4];
    a.Wv      = (const float*)d_in[5];
    a.qln_g   = (const float*)d_in[6];
    a.qln_b   = (const float*)d_in[7];
    a.Wq      = (const float*)d_in[8];
    a.qbg_g   = (const float*)d_in[9];
    a.qbg_b   = (const float*)d_in[10];
    a.Wqbg    = (const float*)d_in[11];
    const float* gru_wih = (const float*)d_in[12];
    const float* gru_whh = (const float*)d_in[13];
    a.gru_bih = (const float*)d_in[14];
    a.gru_bhh = (const float*)d_in[15];
    const float* gbg_wih = (const float*)d_in[16];
    const float* gbg_whh = (const float*)d_in[17];
    a.gbg_bih = (const float*)d_in[18];
    a.gbg_bhh = (const float*)d_in[19];
    a.res_g   = (const float*)d_in[20];
    a.res_b   = (const float*)d_in[21];
    a.res_w1  = (const float*)d_in[22];
    a.res_b1  = (const float*)d_in[23];
    a.res_w2  = (const float*)d_in[24];
    a.res_b2  = (const float*)d_in[25];
    a.rbg_g   = (const float*)d_in[26];
    a.rbg_b   = (const float*)d_in[27];
    a.rbg_w1  = (const float*)d_in[28];
    a.rbg_b1  = (const float*)d_in[29];
    a.rbg_w2  = (const float*)d_in[30];
    a.rbg_b2  = (const float*)d_in[31];

    char* ws = (char*)d_ws;
    size_t off = 0;
    a.fragW = (unsigned short*)(ws + off); off += 16384 * 2;
    off = (off + 255) & ~(size_t)255;
    a.wT    = (float*)(ws + off); off += 4 * DD * 3 * DD * 4;
    a.kT    = (float*)(ws + off); off += (size_t)BB * DD * NN * 4;
    a.v     = (float*)(ws + off); off += (size_t)BB * NN * DD * 4;
    if (off > ws_size) return;  // loud failure rather than corruption

    a.out_slots = (float*)d_out;                 // [B][K][D]
    a.out_attn  = (float*)d_out + BB * KK * DD;  // [B][K][N]

    prep<<<256, 256, 0, stream>>>(a.Wk, a.Wv, gru_wih, gru_whh, gbg_wih, gbg_whh,
                                  a.fragW, a.wT);
    k1_mfma<<<BB * NN / 64, 256, 0, stream>>>(a.feat, a.nf_g, a.nf_b, a.fragW,
                                              a.kT, a.v);
    iter_all<<<BB, 1024, 0, stream>>>(a);
}

// Round 8
// 273.060 us; speedup vs baseline: 3.5664x; 3.5664x over previous
//
#include <hip/hip_runtime.h>
#include <hip/hip_bf16.h>

// Problem constants
constexpr int BB = 32;     // batch
constexpr int NN = 4096;   // tokens
constexpr int CC = 128;    // feat channels
constexpr int DD = 64;     // slot dim
constexpr int KK = 8;      // slots (slot 0 = bg, 1..7 = fg)
constexpr int HH = 128;    // mlp hidden
constexpr float SCALE = 0.125f;   // D^-0.5
constexpr float EPS_A = 1e-8f;
constexpr float LN_EPS = 1e-5f;

constexpr int NTIL = 32;   // 128-token tiles per batch in k2

typedef __bf16 bfx8 __attribute__((ext_vector_type(8)));
typedef float f32x4 __attribute__((ext_vector_type(4)));

__device__ inline float wave_sum(float x) {
#pragma unroll
    for (int off = 32; off > 0; off >>= 1) x += __shfl_xor(x, off, 64);
    return x;
}

__device__ inline float lane_bcast(float v, int src) {
    return __uint_as_float(__builtin_amdgcn_readlane(__float_as_uint(v), src));
}

__device__ inline float sigmoidf_(float x) { return 1.f / (1.f + __expf(-x)); }

__device__ inline unsigned short bf16rne(float x) {
    unsigned u = __float_as_uint(x);
    unsigned r = u + 0x7fffu + ((u >> 16) & 1u);
    return (unsigned short)(r >> 16);
}
__device__ inline float bf16tof(unsigned short h) {
    return __uint_as_float(((unsigned)h) << 16);
}

struct Args {
    const float *feat, *slot_in, *nf_g, *nf_b, *Wk, *Wv;
    const float *qln_g, *qln_b, *Wq, *qbg_g, *qbg_b, *Wqbg;
    const float *gru_bih, *gru_bhh, *gbg_bih, *gbg_bhh;
    const float *res_g, *res_b, *res_w1, *res_b1, *res_w2, *res_b2;
    const float *rbg_g, *rbg_b, *rbg_w1, *rbg_b1, *rbg_w2, *rbg_b2;
    unsigned short *fragW;           // ws
    unsigned short *kT;              // ws, bf16 [b][d][n]
    float *wT, *v, *q, *slots, *Upart, *Spart;   // ws
    float *out_slots, *out_attn;
};

// ---------------------------------------------------------------------------
// prep: blocks 0-63 build fragW ([ks][nf][lane][j] bf16 of [Wk|Wv]);
// blocks 64-255 build wT[m][64][192] transposed GRU weights
// (m: 0=fg_ih 1=fg_hh 2=bg_ih 3=bg_hh).
// ---------------------------------------------------------------------------
__global__ __launch_bounds__(256) void prep(
    const float* __restrict__ Wk, const float* __restrict__ Wv,
    const float* __restrict__ fg_ih, const float* __restrict__ fg_hh,
    const float* __restrict__ bg_ih, const float* __restrict__ bg_hh,
    unsigned short* __restrict__ fragW, float* __restrict__ wT)
{
    const int gid = blockIdx.x, tid = threadIdx.x;
    if (gid < 64) {
        const int o = gid * 256 + tid;   // < 16384
        const int j = o & 7, l = (o >> 3) & 63, nf = (o >> 9) & 7, ks = o >> 12;
        const int c = ks * 32 + ((l >> 4) << 3) + j;
        const int n = nf * 16 + (l & 15);
        const float w = (n < DD) ? Wk[c * DD + n] : Wv[c * DD + (n - DD)];
        fragW[o] = bf16rne(w);
    } else {
        const int o = (gid - 64) * 256 + tid;   // < 49152
        const int m = o / (DD * 3 * DD);
        const int rem = o % (DD * 3 * DD);
        const int d = rem / (3 * DD), j = rem % (3 * DD);
        const float* W = (m == 0) ? fg_ih : (m == 1) ? fg_hh
                       : (m == 2) ? bg_ih : bg_hh;
        wT[o] = W[j * DD + d];
    }
}

// ---------------------------------------------------------------------------
// K1: x = LN(feat); [k|v] = x @ W via bf16 MFMA 2-term split (round-3 verified
// body). kT stored as PACKED bf16 pairs (halves write traffic); v stays
// f32 (coalesced 4B/lane writes from acc).
// ---------------------------------------------------------------------------
__global__ __launch_bounds__(256, 4) void k1_mfma(
    const float* __restrict__ feat, const float* __restrict__ nf_g,
    const float* __restrict__ nf_b, const unsigned short* __restrict__ fragW,
    unsigned short* __restrict__ kT, float* __restrict__ vout)
{
    __shared__ __align__(16) char ubuf[32768];
    const int tid = threadIdx.x, w = tid >> 6, lane = tid & 63;
    const size_t row0 = (size_t)blockIdx.x * 64;
    const float2 g2 = *(const float2*)&nf_g[2 * lane];
    const float2 b2 = *(const float2*)&nf_b[2 * lane];
#pragma unroll 4
    for (int r0 = 0; r0 < 16; r0++) {
        const int r = w * 16 + r0;
        const float2 x2 = *(const float2*)&feat[(row0 + r) * CC + 2 * lane];
        const float m = wave_sum(x2.x + x2.y) * (1.f / 128.f);
        const float d0 = x2.x - m, d1 = x2.y - m;
        const float var = wave_sum(d0 * d0 + d1 * d1) * (1.f / 128.f);
        const float rs = rsqrtf(var + LN_EPS);
        const float y0 = d0 * rs * g2.x + b2.x;
        const float y1 = d1 * rs * g2.y + b2.y;
        const unsigned short h0 = bf16rne(y0), h1 = bf16rne(y1);
        const unsigned short l0 = bf16rne(y0 - bf16tof(h0));
        const unsigned short l1 = bf16rne(y1 - bf16tof(h1));
        const int off = r * 256 + ((4 * lane) ^ ((r & 7) << 4));
        *(unsigned*)(ubuf + off) = (unsigned)h0 | ((unsigned)h1 << 16);
        *(unsigned*)(ubuf + 16384 + off) = (unsigned)l0 | ((unsigned)l1 << 16);
    }
    __syncthreads();
    f32x4 acc[8];
#pragma unroll
    for (int nf = 0; nf < 8; nf++) acc[nf] = (f32x4){0.f, 0.f, 0.f, 0.f};
    const int arow = w * 16 + (lane & 15);
    const int hi16 = lane >> 4;
    const int asw = (arow & 7) << 4;
#pragma unroll
    for (int ks = 0; ks < 4; ks++) {
        const int abyte = arow * 256 + ((ks * 64 + hi16 * 16) ^ asw);
        const bfx8 ah = __builtin_bit_cast(bfx8, *(const uint4*)(ubuf + abyte));
        const bfx8 al = __builtin_bit_cast(bfx8, *(const uint4*)(ubuf + 16384 + abyte));
#pragma unroll
        for (int nf = 0; nf < 8; nf++) {
            const bfx8 bw = __builtin_bit_cast(
                bfx8, *(const uint4*)(fragW + ((ks * 8 + nf) * 64 + lane) * 8));
            acc[nf] = __builtin_amdgcn_mfma_f32_16x16x32_bf16(ah, bw, acc[nf], 0, 0, 0);
            acc[nf] = __builtin_amdgcn_mfma_f32_16x16x32_bf16(al, bw, acc[nf], 0, 0, 0);
        }
    }
    __syncthreads();
    float* kslds = (float*)ubuf;
    const int trow = w * 16 + (lane >> 4) * 4;
#pragma unroll
    for (int nf = 0; nf < 4; nf++) {
        const int d = nf * 16 + (lane & 15);
#pragma unroll
        for (int reg = 0; reg < 4; reg++)
            kslds[d * 65 + trow + reg] = acc[nf][reg];
    }
    {
        const size_t vbase = (row0 + trow) * DD + (lane & 15);
#pragma unroll
        for (int nf = 4; nf < 8; nf++) {
#pragma unroll
            for (int reg = 0; reg < 4; reg++)
                vout[vbase + (size_t)reg * DD + (nf - 4) * 16] = acc[nf][reg];
        }
    }
    __syncthreads();
    const int b = (int)(row0 >> 12);
    const int n0 = (int)(row0 & 4095);
    // packed bf16 kT store: 2 tokens / 4B, coalesced
#pragma unroll
    for (int t = 0; t < 8; t++) {
        const int idx = t * 256 + tid;        // < 2048 = 64 d x 32 pairs
        const int d = idx >> 5, np = idx & 31;
        const unsigned short p0 = bf16rne(kslds[d * 65 + 2 * np]);
        const unsigned short p1 = bf16rne(kslds[d * 65 + 2 * np + 1]);
        *(unsigned*)&kT[((size_t)b * DD + d) * NN + n0 + 2 * np] =
            (unsigned)p0 | ((unsigned)p1 << 16);
    }
}

// ---------------------------------------------------------------------------
// K2: 256 blocks x 256 thr; wave owns 128 tokens (2/lane).  Phase A: dots via
// packed-bf16 k loads (4B/lane coalesced) + qT LDS broadcast; lane-local
// softmax over 8 slots (+eps).  Phase B: lane owns (token-half g, d-pair);
// float2 v loads (512B/instr contiguous); attn via same-address LDS broadcast
// from padded per-wave tile; shfl_xor(32) reduce; per-tile partials out.
// ---------------------------------------------------------------------------
__global__ __launch_bounds__(256) void k2_attn(
    const unsigned short* __restrict__ kT, const float* __restrict__ v,
    const float* __restrict__ q, float* __restrict__ Upart,
    float* __restrict__ Spart, float* __restrict__ attn_out)
{
    __shared__ float qT[DD * KK];        // [d][i], 2 KB
    __shared__ float al[4][128 * 10];    // per-wave attn tile, stride 10, 20 KB

    const int tid = threadIdx.x, w = tid >> 6, lane = tid & 63;
    const int b = blockIdx.x >> 3;
    const int tile = (blockIdx.x & 7) * 4 + w;    // 0..31
    const int n0 = tile * 128;

#pragma unroll
    for (int o = tid; o < DD * KK; o += 256)
        qT[o] = q[((size_t)b * KK + (o & 7)) * DD + (o >> 3)];
    __syncthreads();

    // ---- phase A: dots + softmax (2 tokens per lane) ----
    const unsigned short* kp = kT + (size_t)b * DD * NN + n0 + 2 * lane;
    float dots0[KK], dots1[KK];
#pragma unroll
    for (int i = 0; i < KK; i++) { dots0[i] = 0.f; dots1[i] = 0.f; }
#pragma unroll
    for (int dc = 0; dc < DD; dc += 16) {
        unsigned kb[16];
#pragma unroll
        for (int d = 0; d < 16; d++)
            kb[d] = *(const unsigned*)(kp + (size_t)(dc + d) * NN);
#pragma unroll
        for (int d = 0; d < 16; d++) {
            const float k0 = bf16tof((unsigned short)(kb[d] & 0xffffu));
            const float k1 = bf16tof((unsigned short)(kb[d] >> 16));
            const float4 q0 = *(const float4*)&qT[(dc + d) * 8];
            const float4 q1 = *(const float4*)&qT[(dc + d) * 8 + 4];
            dots0[0] += k0 * q0.x; dots0[1] += k0 * q0.y;
            dots0[2] += k0 * q0.z; dots0[3] += k0 * q0.w;
            dots0[4] += k0 * q1.x; dots0[5] += k0 * q1.y;
            dots0[6] += k0 * q1.z; dots0[7] += k0 * q1.w;
            dots1[0] += k1 * q0.x; dots1[1] += k1 * q0.y;
            dots1[2] += k1 * q0.z; dots1[3] += k1 * q0.w;
            dots1[4] += k1 * q1.x; dots1[5] += k1 * q1.y;
            dots1[6] += k1 * q1.z; dots1[7] += k1 * q1.w;
        }
    }
    float a0[KK], a1[KK], sv[KK];
    {
        float m0 = -1e30f, m1 = -1e30f;
#pragma unroll
        for (int i = 0; i < KK; i++) {
            dots0[i] *= SCALE; dots1[i] *= SCALE;
            m0 = fmaxf(m0, dots0[i]); m1 = fmaxf(m1, dots1[i]);
        }
        float s0 = 0.f, s1 = 0.f;
#pragma unroll
        for (int i = 0; i < KK; i++) {
            a0[i] = __expf(dots0[i] - m0); s0 += a0[i];
            a1[i] = __expf(dots1[i] - m1); s1 += a1[i];
        }
        const float i0 = 1.f / s0, i1 = 1.f / s1;
#pragma unroll
        for (int i = 0; i < KK; i++) {
            a0[i] = a0[i] * i0 + EPS_A;
            a1[i] = a1[i] * i1 + EPS_A;
            sv[i] = a0[i] + a1[i];
        }
    }
    if (attn_out) {
#pragma unroll
        for (int i = 0; i < KK; i++) {
            float2 st = make_float2(a0[i], a1[i]);
            *(float2*)&attn_out[((size_t)b * KK + i) * NN + n0 + 2 * lane] = st;
        }
    }
#pragma unroll
    for (int off = 32; off > 0; off >>= 1) {
#pragma unroll
        for (int i = 0; i < KK; i++) sv[i] += __shfl_xor(sv[i], off, 64);
    }
    if (lane == 0) {
#pragma unroll
        for (int i = 0; i < KK; i++)
            Spart[(size_t)(b * NTIL + tile) * KK + i] = sv[i];
    }
    // stash attn tile (padded stride 10; 2-4 way bank alias only)
    float* alw = &al[w][0];
#pragma unroll
    for (int i = 0; i < KK; i++) {
        alw[(2 * lane) * 10 + i] = a0[i];
        alw[(2 * lane + 1) * 10 + i] = a1[i];
    }
    // no barrier: phase B reads only this wave's own al region

    // ---- phase B: U accumulation (lane owns token-half g, d-pair 2dl) ----
    const int g = lane >> 5, dl = lane & 31;
    const float* vp = v + ((size_t)b * NN + n0 + g) * DD + 2 * dl;
    float U0[KK], U1[KK];
#pragma unroll
    for (int i = 0; i < KK; i++) { U0[i] = 0.f; U1[i] = 0.f; }
#pragma unroll
    for (int s = 0; s < 64; s += 8) {
        float2 vb[8];
#pragma unroll
        for (int u = 0; u < 8; u++)
            vb[u] = *(const float2*)(vp + (size_t)(2 * (s + u)) * DD);
#pragma unroll
        for (int u = 0; u < 8; u++) {
            const float* ap = alw + (2 * (s + u) + g) * 10;
            const float2 p0 = *(const float2*)&ap[0];
            const float2 p1 = *(const float2*)&ap[2];
            const float2 p2 = *(const float2*)&ap[4];
            const float2 p3 = *(const float2*)&ap[6];
            const float vx = vb[u].x, vy = vb[u].y;
            U0[0] += p0.x * vx; U1[0] += p0.x * vy;
            U0[1] += p0.y * vx; U1[1] += p0.y * vy;
            U0[2] += p1.x * vx; U1[2] += p1.x * vy;
            U0[3] += p1.y * vx; U1[3] += p1.y * vy;
            U0[4] += p2.x * vx; U1[4] += p2.x * vy;
            U0[5] += p2.y * vx; U1[5] += p2.y * vy;
            U0[6] += p3.x * vx; U1[6] += p3.x * vy;
            U0[7] += p3.y * vx; U1[7] += p3.y * vy;
        }
    }
#pragma unroll
    for (int i = 0; i < KK; i++) {
        U0[i] += __shfl_xor(U0[i], 32, 64);
        U1[i] += __shfl_xor(U1[i], 32, 64);
    }
    if (lane < 32) {
#pragma unroll
        for (int i = 0; i < KK; i++) {
            float2 st = make_float2(U0[i], U1[i]);
            *(float2*)&Upart[(size_t)(b * NTIL + tile) * (KK * DD) + i * DD + 2 * dl] = st;
        }
    }
}

// ---------------------------------------------------------------------------
// K3: one block of 256 thr per (b, slot).  it<0: init (slots=slot_in, q-gen).
// Else: upd = SUM(Upart)/SUM(Spart) -> GRU (192-thread dual matvec) ->
// residual MLP (128/64-thread matvecs) -> slots -> q-gen.  All weight loads
// coalesced (wT transposed; w1/w2/Wq natural layout).
// ---------------------------------------------------------------------------
__global__ __launch_bounds__(256) void k3_update(Args A, int it)
{
    const int blk = blockIdx.x, b = blk >> 3, i = blk & 7, t = threadIdx.x;
    const int fg = (i != 0);
    const int lane = t & 63;
    __shared__ float h_s[DD], upd_s[DD], red[4][DD], tmp_s[DD], lnx_s[DD],
        h1_s[HH], gi_s[3 * DD], gh_s[3 * DD];
    __shared__ float S_s;

    if (t < DD)
        h_s[t] = (it < 0 ? A.slot_in : A.slots)[((size_t)b * KK + i) * DD + t];

    if (it >= 0) {
        {   // Upart reduce: 4 groups of 8 tiles
            const int pg = t >> 6, d = t & 63;
            float s = 0.f;
#pragma unroll
            for (int p = 0; p < 8; p++)
                s += A.Upart[(size_t)(b * NTIL + pg * 8 + p) * (KK * DD) + i * DD + d];
            red[pg][d] = s;
        }
        if (t < 32) {
            float sp = A.Spart[(size_t)(b * NTIL + t) * KK + i];
#pragma unroll
            for (int off = 16; off > 0; off >>= 1) sp += __shfl_xor(sp, off, 64);
            if (t == 0) S_s = sp;
        }
        __syncthreads();
        if (t < DD)
            upd_s[t] = (red[0][t] + red[1][t] + red[2][t] + red[3][t]) / S_s;
        __syncthreads();

        // GRU dual matvec: thread j<192 computes gi[j] and gh[j]
        if (t < 3 * DD) {
            const float* wih = A.wT + (size_t)(fg ? 0 : 2) * (DD * 3 * DD);
            const float* whh = wih + DD * 3 * DD;
            float gi = (fg ? A.gru_bih : A.gbg_bih)[t];
            float gh = (fg ? A.gru_bhh : A.gbg_bhh)[t];
#pragma unroll 8
            for (int d = 0; d < DD; d++) {
                gi += upd_s[d] * wih[d * 192 + t];
                gh += h_s[d] * whh[d * 192 + t];
            }
            gi_s[t] = gi; gh_s[t] = gh;
        }
        __syncthreads();
        if (t < DD) {
            const float r = sigmoidf_(gi_s[t] + gh_s[t]);
            const float z = sigmoidf_(gi_s[DD + t] + gh_s[DD + t]);
            const float ng = tanhf(gi_s[2 * DD + t] + r * gh_s[2 * DD + t]);
            const float tmp = (1.f - z) * ng + z * h_s[t];
            tmp_s[t] = tmp;
            const float m = wave_sum(tmp) * (1.f / DD);
            const float dv = tmp - m;
            const float var = wave_sum(dv * dv) * (1.f / DD);
            lnx_s[t] = dv * rsqrtf(var + LN_EPS) * (fg ? A.res_g : A.rbg_g)[t] +
                       (fg ? A.res_b : A.rbg_b)[t];
        }
        __syncthreads();
        if (t < HH) {
            const float* w1 = fg ? A.res_w1 : A.rbg_w1;
            float acc = (fg ? A.res_b1 : A.rbg_b1)[t];
#pragma unroll 8
            for (int d = 0; d < DD; d++) acc += lnx_s[d] * w1[d * HH + t];
            h1_s[t] = fmaxf(acc, 0.f);
        }
        __syncthreads();
        if (t < DD) {
            const float* w2 = fg ? A.res_w2 : A.rbg_w2;
            float o = (fg ? A.res_b2 : A.rbg_b2)[t];
#pragma unroll 8
            for (int j = 0; j < HH; j++) o += h1_s[j] * w2[j * DD + t];
            const float newh = tmp_s[t] + o;
            h_s[t] = newh;
            A.slots[((size_t)b * KK + i) * DD + t] = newh;
            if (it == 2) A.out_slots[((size_t)b * KK + i) * DD + t] = newh;
        }
        __syncthreads();
    } else {
        if (t < DD) A.slots[((size_t)b * KK + i) * DD + t] = h_s[t];
        __syncthreads();
    }

    // q-gen on wave 0 (lane-register path, round-5 verified pattern)
    if (t < DD) {
        const float nh = h_s[t];
        const float m2 = wave_sum(nh) * (1.f / DD);
        const float d2 = nh - m2;
        const float v2 = wave_sum(d2 * d2) * (1.f / DD);
        const float lq = d2 * rsqrtf(v2 + LN_EPS) * (fg ? A.qln_g : A.qbg_g)[lane] +
                         (fg ? A.qln_b : A.qbg_b)[lane];
        const float* W = fg ? A.Wq : A.Wqbg;
        float qv = 0.f;
#pragma unroll 4
        for (int e = 0; e < DD; e++)
            qv += lane_bcast(lq, e) * W[e * DD + lane];
        A.q[((size_t)b * KK + i) * DD + lane] = qv;
    }
}

// ---------------------------------------------------------------------------
extern "C" void kernel_launch(void* const* d_in, const int* in_sizes, int n_in,
                              void* d_out, int out_size, void* d_ws, size_t ws_size,
                              hipStream_t stream)
{
    Args a;
    a.feat    = (const float*)d_in[0];
    a.slot_in = (const float*)d_in[1];
    a.nf_g    = (const float*)d_in[2];
    a.nf_b    = (const float*)d_in[3];
    a.Wk      = (const float*)d_in[4];
    a.Wv      = (const float*)d_in[5];
    a.qln_g   = (const float*)d_in[6];
    a.qln_b   = (const float*)d_in[7];
    a.Wq      = (const float*)d_in[8];
    a.qbg_g   = (const float*)d_in[9];
    a.qbg_b   = (const float*)d_in[10];
    a.Wqbg    = (const float*)d_in[11];
    const float* gru_wih = (const float*)d_in[12];
    const float* gru_whh = (const float*)d_in[13];
    a.gru_bih = (const float*)d_in[14];
    a.gru_bhh = (const float*)d_in[15];
    const float* gbg_wih = (const float*)d_in[16];
    const float* gbg_whh = (const float*)d_in[17];
    a.gbg_bih = (const float*)d_in[18];
    a.gbg_bhh = (const float*)d_in[19];
    a.res_g   = (const float*)d_in[20];
    a.res_b   = (const float*)d_in[21];
    a.res_w1  = (const float*)d_in[22];
    a.res_b1  = (const float*)d_in[23];
    a.res_w2  = (const float*)d_in[24];
    a.res_b2  = (const float*)d_in[25];
    a.rbg_g   = (const float*)d_in[26];
    a.rbg_b   = (const float*)d_in[27];
    a.rbg_w1  = (const float*)d_in[28];
    a.rbg_b1  = (const float*)d_in[29];
    a.rbg_w2  = (const float*)d_in[30];
    a.rbg_b2  = (const float*)d_in[31];

    char* ws = (char*)d_ws;
    size_t off = 0;
    a.fragW = (unsigned short*)(ws + off); off += 16384 * 2;
    off = (off + 255) & ~(size_t)255;
    a.wT    = (float*)(ws + off); off += 4 * DD * 3 * DD * 4;
    a.kT    = (unsigned short*)(ws + off); off += (size_t)BB * DD * NN * 2;
    off = (off + 255) & ~(size_t)255;
    a.v     = (float*)(ws + off); off += (size_t)BB * NN * DD * 4;
    a.q     = (float*)(ws + off); off += (size_t)BB * KK * DD * 4;
    a.slots = (float*)(ws + off); off += (size_t)BB * KK * DD * 4;
    a.Upart = (float*)(ws + off); off += (size_t)BB * NTIL * KK * DD * 4;
    a.Spart = (float*)(ws + off); off += (size_t)BB * NTIL * KK * 4;
    if (off > ws_size) return;  // loud failure rather than corruption

    a.out_slots = (float*)d_out;                 // [B][K][D]
    a.out_attn  = (float*)d_out + BB * KK * DD;  // [B][K][N]

    prep<<<256, 256, 0, stream>>>(a.Wk, a.Wv, gru_wih, gru_whh, gbg_wih, gbg_whh,
                                  a.fragW, a.wT);
    k3_update<<<BB * KK, 256, 0, stream>>>(a, -1);
    k1_mfma<<<BB * NN / 64, 256, 0, stream>>>(a.feat, a.nf_g, a.nf_b, a.fragW,
                                              a.kT, a.v);
    for (int it = 0; it < 3; it++) {
        k2_attn<<<BB * 8, 256, 0, stream>>>(
            a.kT, a.v, a.q, a.Upart, a.Spart, it == 2 ? a.out_attn : nullptr);
        k3_update<<<BB * KK, 256, 0, stream>>>(a, it);
    }
}